// Round 5
// baseline (71.849 us; speedup 1.0000x reference)
//
#include <hip/hip_runtime.h>
#include <math.h>

#define HH 256
#define WW 256
#define EPS2D 1e-4f
#define MAXN 1024
#define NPIX (HH*WW)
#define CULL_THR 23.0f   // skip gaussian in a strip if max alpha there < 2^-23

// Record: 3 x float4 per gaussian, depth-sorted front-to-back:
// [mx, my, qa, qb] [qc, lk, cr, cg] [cb, 0, 0, 0]
// alpha = exp2( qa*dx*dx + qb*dx*dy + qc*dy*dy + lk ),  qa,qc < 0

__global__ __launch_bounds__(256) void prep_kernel(
    const float* __restrict__ means3D, const float* __restrict__ covs3d,
    const float* __restrict__ colors,  const float* __restrict__ opac,
    const float* __restrict__ Km,      const float* __restrict__ Rm,
    const float* __restrict__ tv,      float4* __restrict__ rec, int n)
{
    __shared__ float s_mean[MAXN*3];   // all means (12 KB)
    __shared__ float s_depth[MAXN];    // all depths (4 KB)
    __shared__ float s_cov[256*9];     // this block's covs (9 KB)
    __shared__ float s_col[256*3];
    __shared__ float s_op[256];

    int t = threadIdx.x;
    int g0b = blockIdx.x << 8;
    int nb = n - g0b; if (nb > 256) nb = 256; if (nb < 0) nb = 0;

    // ---- coalesced staging ----
    {
        int nm4 = (3*n) >> 2;
        const float4* m4 = (const float4*)means3D;
        for (int i = t; i < nm4; i += 256) ((float4*)s_mean)[i] = m4[i];
        for (int i = (nm4<<2) + t; i < 3*n; i += 256) s_mean[i] = means3D[i];

        const float* cbase = covs3d + (size_t)g0b * 9;
        int ncf = nb * 9, nc4 = ncf >> 2;
        for (int i = t; i < nc4; i += 256) ((float4*)s_cov)[i] = ((const float4*)cbase)[i];
        for (int i = (nc4<<2) + t; i < ncf; i += 256) s_cov[i] = cbase[i];

        const float* lbase = colors + (size_t)g0b * 3;
        int nlf = nb * 3, nl4 = nlf >> 2;
        for (int i = t; i < nl4; i += 256) ((float4*)s_col)[i] = ((const float4*)lbase)[i];
        for (int i = (nl4<<2) + t; i < nlf; i += 256) s_col[i] = lbase[i];

        const float* obase = opac + g0b;
        int no4 = nb >> 2;
        for (int i = t; i < no4; i += 256) ((float4*)s_op)[i] = ((const float4*)obase)[i];
        for (int i = (no4<<2) + t; i < nb; i += 256) s_op[i] = obase[i];
    }
    __syncthreads();

    float R00=Rm[0],R01=Rm[1],R02=Rm[2];
    float R10=Rm[3],R11=Rm[4],R12=Rm[5];
    float R20=Rm[6],R21=Rm[7],R22=Rm[8];
    float t0=tv[0], t1=tv[1], t2=tv[2];

    // ---- all depths from LDS means ----
    for (int g = t; g < MAXN; g += 256) {
        float d = 1e30f;
        if (g < n) {
            float X=s_mean[3*g+0], Y=s_mean[3*g+1], Z=s_mean[3*g+2];
            float cz = R20*X + R21*Y + R22*Z + t2;
            d = fmaxf(cz, 1.0f);
        }
        s_depth[g] = d;
    }
    __syncthreads();

    if (t >= nb) return;
    int i = g0b + t;

    float X = s_mean[3*i+0], Y = s_mean[3*i+1], Z = s_mean[3*i+2];
    float cx = R00*X + R01*Y + R02*Z + t0;
    float cy = R10*X + R11*Y + R12*Z + t1;
    float cz = R20*X + R21*Y + R22*Z + t2;
    float depth = s_depth[i];

    float K00=Km[0],K01=Km[1],K02=Km[2];
    float K10=Km[3],K11=Km[4],K12=Km[5];
    float K20=Km[6],K21=Km[7],K22=Km[8];
    float sx = K00*cx + K01*cy + K02*cz;
    float sy = K10*cx + K11*cy + K12*cz;
    float sz = K20*cx + K21*cy + K22*cz;
    float mx = sx / sz;
    float my = sy / sz;

    float fx = K00, fy = K11;
    float invz  = 1.0f / cz;
    float invz2 = invz * invz;
    float j00 =  fx * invz;
    float j02 = -fx * cx * invz2;
    float j11 =  fy * invz;
    float j12 = -fy * cy * invz2;

    const float* S = s_cov + 9*t;
    float S00=S[0],S01=S[1],S02=S[2];
    float S10=S[3],S11=S[4],S12=S[5];
    float S20=S[6],S21=S[7],S22=S[8];

    float M00 = R00*S00 + R01*S10 + R02*S20;
    float M01 = R00*S01 + R01*S11 + R02*S21;
    float M02 = R00*S02 + R01*S12 + R02*S22;
    float M10 = R10*S00 + R11*S10 + R12*S20;
    float M11 = R10*S01 + R11*S11 + R12*S21;
    float M12 = R10*S02 + R11*S12 + R12*S22;
    float M20 = R20*S00 + R21*S10 + R22*S20;
    float M21 = R20*S01 + R21*S11 + R22*S21;
    float M22 = R20*S02 + R21*S12 + R22*S22;
    float C00 = M00*R00 + M01*R01 + M02*R02;
    float C01 = M00*R10 + M01*R11 + M02*R12;
    float C02 = M00*R20 + M01*R21 + M02*R22;
    float C11 = M10*R10 + M11*R11 + M12*R12;
    float C12 = M10*R20 + M11*R21 + M12*R22;
    float C22 = M20*R20 + M21*R21 + M22*R22;

    float a_ = j00*j00*C00 + 2.0f*j00*j02*C02 + j02*j02*C22 + EPS2D;
    float b_ = j00*j11*C01 + j00*j12*C02 + j02*j11*C12 + j02*j12*C22;
    float c_ = j11*j11*C11 + 2.0f*j11*j12*C12 + j12*j12*C22 + EPS2D;

    float det = a_ * c_ - b_ * b_;
    float ia =  c_ / det;
    float ib = -b_ / det;
    float ic =  a_ / det;
    float norm = 1.0f / (6.283185307179586f * sqrtf(det));

    bool valid = (depth > 1.0f) && (depth < 50.0f);
    float k = s_op[t] * norm * (valid ? 1.0f : 0.0f);

    const float NL = -0.72134752044448170368f; // -0.5 * log2(e)
    float qa = NL * ia;
    float qb = 2.0f * NL * ib;
    float qc = NL * ic;
    float lk = log2f(k);   // -inf when k==0

    float cr = s_col[3*t+0];
    float cg = s_col[3*t+1];
    float cb = s_col[3*t+2];

    // stable rank over LDS depths (float4-vectorized)
    int rank = 0;
    const float4* d4 = (const float4*)s_depth;
    int n4 = n >> 2;
    for (int j4 = 0; j4 < n4; ++j4) {
        float4 v = d4[j4];
        int j = 4*j4;
        rank += (v.x < depth || (v.x == depth && j+0 < i)) ? 1 : 0;
        rank += (v.y < depth || (v.y == depth && j+1 < i)) ? 1 : 0;
        rank += (v.z < depth || (v.z == depth && j+2 < i)) ? 1 : 0;
        rank += (v.w < depth || (v.w == depth && j+3 < i)) ? 1 : 0;
    }
    for (int j = n4*4; j < n; ++j) {
        float dj = s_depth[j];
        rank += (dj < depth || (dj == depth && j < i)) ? 1 : 0;
    }

    rec[3*rank+0] = make_float4(mx, my, qa, qb);
    rec[3*rank+1] = make_float4(qc, lk, cr, cg);
    rec[3*rank+2] = make_float4(cb, 0.f, 0.f, 0.f);
}

// Render: grid (HH/2, seg), block 256 = 4 waves over a 2-row strip.
// wave w: row = 2*bx + (w>>1), x-half = (w&1)*128; 2 px/thread (x, x+64).
extern __shared__ char smem[];

__global__ __launch_bounds__(256) void render_kernel(
    const float4* __restrict__ rec, float4* __restrict__ part,
    float* __restrict__ out, int n, int cnt, int direct)
{
    int s  = blockIdx.y;
    int gb = s * cnt;
    int m  = min(n, gb + cnt) - gb;
    if (m < 0) m = 0;

    float4* s_rec = (float4*)smem;                       // 3*cnt float4
    int*    s_idx = (int*)(smem + (size_t)cnt * 48);     // cnt ints
    __shared__ int s_w[4];
    __shared__ int s_total;

    int t = threadIdx.x, lane = t & 63, wid = t >> 6;
    if (t == 0) s_total = 0;
    __syncthreads();

    float ylo = (float)(blockIdx.x * 2);
    float yhi = ylo + 1.0f;

    // ---- cull + order-stable compaction ----
    for (int c = 0; c < m; c += 256) {
        int j = c + t;
        bool keep = false;
        if (j < m) {
            float4 v0 = rec[3*(gb+j)+0];
            float4 v1 = rec[3*(gb+j)+1];
            float qa = v0.z, qb = v0.w, qc = v1.x, lk = v1.y;
            float cc = lk + CULL_THR;
            if (cc > 0.0f) {
                float dpp = fmaf(4.0f*qa, qc, -qb*qb);   // 4*qa*qc - qb^2 > 0
                float inv = cc / dpp;
                float dxe = sqrtf(fmaxf(-4.0f*qc*inv, 0.0f));
                float dye = sqrtf(fmaxf(-4.0f*qa*inv, 0.0f));
                keep = (v0.x + dxe >= 0.0f)  && (v0.x - dxe <= 255.0f) &&
                       (v0.y + dye >= ylo)   && (v0.y - dye <= yhi);
            }
        }
        unsigned long long mk = __ballot(keep);
        int pre = __popcll(mk & ((1ull << lane) - 1ull));
        if (lane == 0) s_w[wid] = __popcll(mk);
        __syncthreads();
        int base = s_total;
        for (int w = 0; w < wid; ++w) base += s_w[w];
        if (keep) s_idx[base + pre] = j;
        __syncthreads();
        if (t == 0) s_total += s_w[0] + s_w[1] + s_w[2] + s_w[3];
        __syncthreads();
    }
    int sc = s_total;

    // ---- stage survivor records compacted into LDS ----
    for (int k = t; k < sc; k += 256) {
        int j = s_idx[k];
        s_rec[3*k+0] = rec[3*(gb+j)+0];
        s_rec[3*k+1] = rec[3*(gb+j)+1];
        s_rec[3*k+2] = rec[3*(gb+j)+2];
    }
    __syncthreads();

    const float* s_f = (const float*)s_rec;
    int   row   = (blockIdx.x << 1) + (wid >> 1);
    float pyf   = (float)row;
    float x0    = (float)(((wid & 1) << 7) + lane);

    float T0=1.f,T1=1.f;
    float r0=0.f,r1=0.f,g0=0.f,g1=0.f,b0=0.f,b1=0.f;

    for (int k = 0; k < sc; ++k) {
        float4 v0 = s_rec[3*k+0];
        float4 v1 = s_rec[3*k+1];
        float  cb = s_f[12*k+8];

        float dy  = pyf - v0.y;
        float vb  = v0.w * dy;                   // qb*dy
        float u   = fmaf(v1.x * dy, dy, v1.y);   // qc*dy^2 + lk
        float dx0 = x0 - v0.x;

        {
            float dx = dx0;
            float q = fmaf(fmaf(v0.z, dx, vb), dx, u);
            float w = T0 * __builtin_amdgcn_exp2f(q);
            r0 = fmaf(w, v1.z, r0); g0 = fmaf(w, v1.w, g0); b0 = fmaf(w, cb, b0); T0 -= w;
        }
        {
            float dx = dx0 + 64.0f;
            float q = fmaf(fmaf(v0.z, dx, vb), dx, u);
            float w = T1 * __builtin_amdgcn_exp2f(q);
            r1 = fmaf(w, v1.z, r1); g1 = fmaf(w, v1.w, g1); b1 = fmaf(w, cb, b1); T1 -= w;
        }

        if ((k & 15) == 15) {
            if (__all(fmaxf(T0, T1) < 1e-7f)) break;
        }
    }

    int pbase = row * 256 + ((wid & 1) << 7) + lane;
    if (direct) {
        out[3*(pbase+ 0)+0]=r0; out[3*(pbase+ 0)+1]=g0; out[3*(pbase+ 0)+2]=b0;
        out[3*(pbase+64)+0]=r1; out[3*(pbase+64)+1]=g1; out[3*(pbase+64)+2]=b1;
    } else {
        part[s*NPIX + pbase +  0] = make_float4(r0, g0, b0, T0);
        part[s*NPIX + pbase + 64] = make_float4(r1, g1, b1, T1);
    }
}

__global__ __launch_bounds__(256) void combine_kernel(
    const float4* __restrict__ part, float* __restrict__ out, int seg)
{
    int p = blockIdx.x * 256 + threadIdx.x;
    float r = 0.f, g = 0.f, b = 0.f, T = 1.0f;
    for (int s = 0; s < seg; ++s) {
        float4 v = part[s * NPIX + p];
        r = fmaf(T, v.x, r);
        g = fmaf(T, v.y, g);
        b = fmaf(T, v.z, b);
        T *= v.w;
    }
    out[3*p+0] = r;
    out[3*p+1] = g;
    out[3*p+2] = b;
}

extern "C" void kernel_launch(void* const* d_in, const int* in_sizes, int n_in,
                              void* d_out, int out_size, void* d_ws, size_t ws_size,
                              hipStream_t stream)
{
    const float* means3D = (const float*)d_in[0];
    const float* covs3d  = (const float*)d_in[1];
    const float* colors  = (const float*)d_in[2];
    const float* opac    = (const float*)d_in[3];
    const float* Km      = (const float*)d_in[4];
    const float* Rm      = (const float*)d_in[5];
    const float* tv      = (const float*)d_in[6];
    int n = in_sizes[3];
    if (n > MAXN) n = MAXN;

    float4* rec = (float4*)d_ws;                 // 48 KB max
    const size_t base = 64 * 1024;

    int seg = 1, direct = 1;
    if      (ws_size >= base + (size_t)8 * NPIX * 16) { seg = 8; direct = 0; }
    else if (ws_size >= base + (size_t)4 * NPIX * 16) { seg = 4; direct = 0; }
    else if (ws_size >= base + (size_t)2 * NPIX * 16) { seg = 2; direct = 0; }
    else if (ws_size >= base + (size_t)1 * NPIX * 16) { seg = 1; direct = 0; }

    int cnt = (n + seg - 1) / seg;
    float4* part = (float4*)((char*)d_ws + base);
    size_t shbytes = (size_t)cnt * 48 + (size_t)cnt * 4;

    int pblocks = (n + 255) / 256;
    hipLaunchKernelGGL(prep_kernel, dim3(pblocks), dim3(256), 0, stream,
                       means3D, covs3d, colors, opac, Km, Rm, tv, rec, n);

    hipLaunchKernelGGL(render_kernel, dim3(HH/2, seg), dim3(256),
                       shbytes, stream, rec, part, (float*)d_out, n, cnt, direct);

    if (!direct) {
        hipLaunchKernelGGL(combine_kernel, dim3(NPIX/256), dim3(256), 0, stream,
                           part, (float*)d_out, seg);
    }
}

// Round 6
// 56.195 us; speedup vs baseline: 1.2786x; 1.2786x over previous
//
#include <hip/hip_runtime.h>
#include <math.h>

#define HH 256
#define WW 256
#define EPS2D 1e-4f
#define MAXN 1024
#define NPIX (HH*WW)
#define CULL_THR 23.0f   // skip gaussian in a window if max alpha there < 2^-23
#define RTHR 1e-7f

// SoA records, depth-sorted front-to-back (in d_ws):
//   A[g] = (mx, my, qa, qb)   B[g] = (qc, lk, cr, cg)   C[g] = cb
// alpha = exp2( qa*dx*dx + qb*dx*dy + qc*dy*dy + lk ),  qa,qc < 0

__global__ __launch_bounds__(64) void prep_kernel(
    const float* __restrict__ means3D, const float* __restrict__ covs3d,
    const float* __restrict__ colors,  const float* __restrict__ opac,
    const float* __restrict__ Km,      const float* __restrict__ Rm,
    const float* __restrict__ tv,
    float4* __restrict__ A, float4* __restrict__ B, float* __restrict__ C,
    int n)
{
    __shared__ float s_mean[MAXN*3];   // all means (12 KB)
    __shared__ float s_depth[MAXN];    // all depths (4 KB)
    __shared__ float s_cov[64*9];      // this block's covs
    __shared__ float s_col[64*3];
    __shared__ float s_op[64];

    int t = threadIdx.x;
    int g0b = blockIdx.x * 64;
    int nb = n - g0b; if (nb > 64) nb = 64; if (nb < 0) nb = 0;

    // ---- coalesced staging ----
    {
        int nm4 = (3*n) >> 2;
        const float4* m4 = (const float4*)means3D;
        for (int i = t; i < nm4; i += 64) ((float4*)s_mean)[i] = m4[i];
        for (int i = (nm4<<2) + t; i < 3*n; i += 64) s_mean[i] = means3D[i];

        const float* cbase = covs3d + (size_t)g0b * 9;
        int ncf = nb * 9, nc4 = ncf >> 2;
        for (int i = t; i < nc4; i += 64) ((float4*)s_cov)[i] = ((const float4*)cbase)[i];
        for (int i = (nc4<<2) + t; i < ncf; i += 64) s_cov[i] = cbase[i];

        const float* lbase = colors + (size_t)g0b * 3;
        int nlf = nb * 3, nl4 = nlf >> 2;
        for (int i = t; i < nl4; i += 64) ((float4*)s_col)[i] = ((const float4*)lbase)[i];
        for (int i = (nl4<<2) + t; i < nlf; i += 64) s_col[i] = lbase[i];

        const float* obase = opac + g0b;
        int no4 = nb >> 2;
        for (int i = t; i < no4; i += 64) ((float4*)s_op)[i] = ((const float4*)obase)[i];
        for (int i = (no4<<2) + t; i < nb; i += 64) s_op[i] = obase[i];
    }
    __syncthreads();

    float R00=Rm[0],R01=Rm[1],R02=Rm[2];
    float R10=Rm[3],R11=Rm[4],R12=Rm[5];
    float R20=Rm[6],R21=Rm[7],R22=Rm[8];
    float t0=tv[0], t1=tv[1], t2=tv[2];

    // ---- all depths (redundant per block, cheap) ----
    for (int g = t; g < n; g += 64) {
        float X=s_mean[3*g+0], Y=s_mean[3*g+1], Z=s_mean[3*g+2];
        float cz = R20*X + R21*Y + R22*Z + t2;
        s_depth[g] = fmaxf(cz, 1.0f);
    }
    __syncthreads();

    if (t >= nb) return;
    int i = g0b + t;

    float X = s_mean[3*i+0], Y = s_mean[3*i+1], Z = s_mean[3*i+2];
    float cx = R00*X + R01*Y + R02*Z + t0;
    float cy = R10*X + R11*Y + R12*Z + t1;
    float cz = R20*X + R21*Y + R22*Z + t2;
    float depth = s_depth[i];

    float K00=Km[0],K01=Km[1],K02=Km[2];
    float K10=Km[3],K11=Km[4],K12=Km[5];
    float K20=Km[6],K21=Km[7],K22=Km[8];
    float sx = K00*cx + K01*cy + K02*cz;
    float sy = K10*cx + K11*cy + K12*cz;
    float sz = K20*cx + K21*cy + K22*cz;
    float mx = sx / sz;
    float my = sy / sz;

    float fx = K00, fy = K11;
    float invz  = 1.0f / cz;
    float invz2 = invz * invz;
    float j00 =  fx * invz;
    float j02 = -fx * cx * invz2;
    float j11 =  fy * invz;
    float j12 = -fy * cy * invz2;

    const float* S = s_cov + 9*t;
    float S00=S[0],S01=S[1],S02=S[2];
    float S10=S[3],S11=S[4],S12=S[5];
    float S20=S[6],S21=S[7],S22=S[8];

    float M00 = R00*S00 + R01*S10 + R02*S20;
    float M01 = R00*S01 + R01*S11 + R02*S21;
    float M02 = R00*S02 + R01*S12 + R02*S22;
    float M10 = R10*S00 + R11*S10 + R12*S20;
    float M11 = R10*S01 + R11*S11 + R12*S21;
    float M12 = R10*S02 + R11*S12 + R12*S22;
    float M20 = R20*S00 + R21*S10 + R22*S20;
    float M21 = R20*S01 + R21*S11 + R22*S21;
    float M22 = R20*S02 + R21*S12 + R22*S22;
    float C00 = M00*R00 + M01*R01 + M02*R02;
    float C01 = M00*R10 + M01*R11 + M02*R12;
    float C02 = M00*R20 + M01*R21 + M02*R22;
    float C11 = M10*R10 + M11*R11 + M12*R12;
    float C12 = M10*R20 + M11*R21 + M12*R22;
    float C22 = M20*R20 + M21*R21 + M22*R22;

    float a_ = j00*j00*C00 + 2.0f*j00*j02*C02 + j02*j02*C22 + EPS2D;
    float b_ = j00*j11*C01 + j00*j12*C02 + j02*j11*C12 + j02*j12*C22;
    float c_ = j11*j11*C11 + 2.0f*j11*j12*C12 + j12*j12*C22 + EPS2D;

    float det = a_ * c_ - b_ * b_;
    float ia =  c_ / det;
    float ib = -b_ / det;
    float ic =  a_ / det;
    float norm = 1.0f / (6.283185307179586f * sqrtf(det));

    bool valid = (depth > 1.0f) && (depth < 50.0f);
    float k = s_op[t] * norm * (valid ? 1.0f : 0.0f);

    const float NL = -0.72134752044448170368f; // -0.5 * log2(e)
    float qa = NL * ia;
    float qb = 2.0f * NL * ib;
    float qc = NL * ic;
    float lk = log2f(k);   // -inf when k==0

    // stable rank over LDS depths (float4-vectorized)
    int rank = 0;
    const float4* d4 = (const float4*)s_depth;
    int n4 = n >> 2;
    for (int j4 = 0; j4 < n4; ++j4) {
        float4 v = d4[j4];
        int j = 4*j4;
        rank += (v.x < depth || (v.x == depth && j+0 < i)) ? 1 : 0;
        rank += (v.y < depth || (v.y == depth && j+1 < i)) ? 1 : 0;
        rank += (v.z < depth || (v.z == depth && j+2 < i)) ? 1 : 0;
        rank += (v.w < depth || (v.w == depth && j+3 < i)) ? 1 : 0;
    }
    for (int j = n4*4; j < n; ++j) {
        float dj = s_depth[j];
        rank += (dj < depth || (dj == depth && j < i)) ? 1 : 0;
    }

    A[rank] = make_float4(mx, my, qa, qb);
    B[rank] = make_float4(qc, lk, s_col[3*t+0], s_col[3*t+1]);
    C[rank] = s_col[3*t+2];
}

// Render: grid = 256 blocks (one per row), 256 threads = 4 waves.
// wave w: x-half = w&1 (x in [128*(w&1), +128)), candidate-half = w>>1
// (front [0,nh) / back [nh,n)). Each wave: private cull -> idx list ->
// chunked gather-stage -> composite 2 px/thread. One __syncthreads to
// merge front/back halves through LDS.
__global__ __launch_bounds__(256) void render_kernel(
    const float4* __restrict__ A, const float4* __restrict__ B,
    const float* __restrict__ C, float* __restrict__ out, int n)
{
    __shared__ int    s_idx[4][512];
    __shared__ float4 s_ga[4][64];
    __shared__ float4 s_gb[4][64];
    __shared__ float  s_gc[4][64];
    __shared__ float4 s_part[256];

    int t = threadIdx.x, lane = t & 63, w = t >> 6;
    int row  = blockIdx.x;
    int xh   = w & 1;
    int half = w >> 1;
    int nh   = (n + 1) >> 1;
    int c0   = half ? nh : 0;
    int c1   = half ? n  : nh;

    float xlo = (float)(xh << 7);
    float xhi = xlo + 127.0f;
    float pyf = (float)row;

    // ---- per-wave cull -> order-stable idx list ----
    int cnt = 0;
    for (int c = c0; c < c1; c += 64) {
        int j = c + lane;
        bool keep = false;
        if (j < c1) {
            float4 a = A[j];
            float4 b = B[j];
            float cc = b.y + CULL_THR;          // lk + THR
            if (cc > 0.0f) {
                float dpp = fmaf(4.0f*a.z, b.x, -a.w*a.w);  // 4*qa*qc - qb^2 > 0
                float inv = cc / dpp;
                float dxe = sqrtf(fmaxf(-4.0f*b.x*inv, 0.0f));
                float dye = sqrtf(fmaxf(-4.0f*a.z*inv, 0.0f));
                keep = (a.x + dxe >= xlo) && (a.x - dxe <= xhi) &&
                       (a.y + dye >= pyf) && (a.y - dye <= pyf);
            }
        }
        unsigned long long mk = __ballot(keep);
        int pre = __popcll(mk & ((1ull << lane) - 1ull));
        if (keep) s_idx[w][cnt + pre] = j;
        cnt += __popcll(mk);
    }

    // ---- chunked gather-stage + composite (wave-private, no barriers) ----
    float x0 = xlo + (float)lane;
    float T0=1.f, T1=1.f;
    float r0=0.f, g0=0.f, b0=0.f, r1=0.f, g1=0.f, b1=0.f;

    for (int k0 = 0; k0 < cnt; k0 += 64) {
        int m = cnt - k0; if (m > 64) m = 64;
        if (lane < m) {
            int jj = s_idx[w][k0 + lane];
            s_ga[w][lane] = A[jj];
            s_gb[w][lane] = B[jj];
            s_gc[w][lane] = C[jj];
        }
        for (int k = 0; k < m; ++k) {
            float4 va = s_ga[w][k];
            float4 vb = s_gb[w][k];
            float  cc = s_gc[w][k];

            float dy   = pyf - va.y;
            float qbdy = va.w * dy;
            float u    = fmaf(vb.x * dy, dy, vb.y);
            float dx0  = x0 - va.x;
            {
                float q = fmaf(fmaf(va.z, dx0, qbdy), dx0, u);
                float e = __builtin_amdgcn_exp2f(q);
                float wg = T0 * e;
                r0 = fmaf(wg, vb.z, r0); g0 = fmaf(wg, vb.w, g0);
                b0 = fmaf(wg, cc, b0);  T0 -= wg;
            }
            {
                float dx1 = dx0 + 64.0f;
                float q = fmaf(fmaf(va.z, dx1, qbdy), dx1, u);
                float e = __builtin_amdgcn_exp2f(q);
                float wg = T1 * e;
                r1 = fmaf(wg, vb.z, r1); g1 = fmaf(wg, vb.w, g1);
                b1 = fmaf(wg, cc, b1);  T1 -= wg;
            }
            if ((k & 15) == 15) {
                if (__all(fmaxf(T0, T1) < RTHR)) break;
            }
        }
        if (__all(fmaxf(T0, T1) < RTHR)) break;
    }

    // ---- merge front/back through LDS ----
    int lpx = (xh << 7) + lane;          // local pixel x (0..255)
    if (half) {
        s_part[lpx]      = make_float4(r0, g0, b0, T0);
        s_part[lpx + 64] = make_float4(r1, g1, b1, T1);
    }
    __syncthreads();
    if (!half) {
        float4 p0 = s_part[lpx];
        float4 p1 = s_part[lpx + 64];
        int p = row * 256 + lpx;
        out[3*p+0] = fmaf(T0, p0.x, r0);
        out[3*p+1] = fmaf(T0, p0.y, g0);
        out[3*p+2] = fmaf(T0, p0.z, b0);
        p += 64;
        out[3*p+0] = fmaf(T1, p1.x, r1);
        out[3*p+1] = fmaf(T1, p1.y, g1);
        out[3*p+2] = fmaf(T1, p1.z, b1);
    }
}

extern "C" void kernel_launch(void* const* d_in, const int* in_sizes, int n_in,
                              void* d_out, int out_size, void* d_ws, size_t ws_size,
                              hipStream_t stream)
{
    const float* means3D = (const float*)d_in[0];
    const float* covs3d  = (const float*)d_in[1];
    const float* colors  = (const float*)d_in[2];
    const float* opac    = (const float*)d_in[3];
    const float* Km      = (const float*)d_in[4];
    const float* Rm      = (const float*)d_in[5];
    const float* tv      = (const float*)d_in[6];
    int n = in_sizes[3];
    if (n > MAXN) n = MAXN;

    float4* A = (float4*)d_ws;                          // 16 KB
    float4* B = (float4*)((char*)d_ws + 16384);         // 16 KB
    float*  C = (float*)((char*)d_ws + 32768);          // 4 KB

    int pblocks = (n + 63) / 64;
    hipLaunchKernelGGL(prep_kernel, dim3(pblocks), dim3(64), 0, stream,
                       means3D, covs3d, colors, opac, Km, Rm, tv, A, B, C, n);

    hipLaunchKernelGGL(render_kernel, dim3(HH), dim3(256), 0, stream,
                       A, B, C, (float*)d_out, n);
}

// Round 7
// 31.960 us; speedup vs baseline: 2.2481x; 1.7583x over previous
//
#include <hip/hip_runtime.h>
#include <math.h>

#define HH 256
#define WW 256
#define EPS2D 1e-4f
#define MAXN 1024
#define CULL_THR 23.0f   // skip gaussian in a window if max alpha there < 2^-23
#define RTHR 1e-7f

// SoA records, depth-sorted front-to-back (in d_ws):
//   A[g] = (mx, my, qa, qb)   B[g] = (qc, lk, cr, cg)   C[g] = cb
// alpha = exp2( qa*dx*dx + qb*dx*dy + qc*dy*dy + lk ),  qa,qc < 0

// prep: grid = ceil(n/64) blocks x 256 threads (4 waves).
// Block b owns gaussians [64b, 64b+64). Wave w computes partial ranks over
// depth quarter [256w, 256w+256) (broadcast float4 reads); wave 0 does the
// projection math lane-parallel; one barrier; wave 0 combines + scatters.
__global__ __launch_bounds__(256) void prep_kernel(
    const float* __restrict__ means3D, const float* __restrict__ covs3d,
    const float* __restrict__ colors,  const float* __restrict__ opac,
    const float* __restrict__ Km,      const float* __restrict__ Rm,
    const float* __restrict__ tv,
    float4* __restrict__ A, float4* __restrict__ B, float* __restrict__ C,
    int n)
{
    __shared__ float s_mean[MAXN*3];   // all means (12 KB)
    __shared__ float s_depth[MAXN];    // all depths (4 KB)
    __shared__ float s_cov[64*9];
    __shared__ float s_col[64*3];
    __shared__ float s_op[64];
    __shared__ int   s_pr[4][64];

    int t = threadIdx.x, lane = t & 63, w = t >> 6;
    int g0b = blockIdx.x * 64;
    int nb = n - g0b; if (nb > 64) nb = 64; if (nb < 0) nb = 0;

    // ---- coalesced staging ----
    {
        int nm4 = (3*n) >> 2;
        const float4* m4 = (const float4*)means3D;
        for (int i = t; i < nm4; i += 256) ((float4*)s_mean)[i] = m4[i];
        for (int i = (nm4<<2) + t; i < 3*n; i += 256) s_mean[i] = means3D[i];

        const float* cbase = covs3d + (size_t)g0b * 9;
        int ncf = nb * 9, nc4 = ncf >> 2;
        for (int i = t; i < nc4; i += 256) ((float4*)s_cov)[i] = ((const float4*)cbase)[i];
        for (int i = (nc4<<2) + t; i < ncf; i += 256) s_cov[i] = cbase[i];

        const float* lbase = colors + (size_t)g0b * 3;
        int nlf = nb * 3, nl4 = nlf >> 2;
        for (int i = t; i < nl4; i += 256) ((float4*)s_col)[i] = ((const float4*)lbase)[i];
        for (int i = (nl4<<2) + t; i < nlf; i += 256) s_col[i] = lbase[i];

        const float* obase = opac + g0b;
        int no4 = nb >> 2;
        for (int i = t; i < no4; i += 256) ((float4*)s_op)[i] = ((const float4*)obase)[i];
        for (int i = (no4<<2) + t; i < nb; i += 256) s_op[i] = obase[i];
    }
    __syncthreads();

    float R00=Rm[0],R01=Rm[1],R02=Rm[2];
    float R10=Rm[3],R11=Rm[4],R12=Rm[5];
    float R20=Rm[6],R21=Rm[7],R22=Rm[8];
    float t0=tv[0], t1=tv[1], t2=tv[2];

    // ---- all depths ----
    for (int g = t; g < MAXN; g += 256) {
        float d = 1e30f;
        if (g < n) {
            float X=s_mean[3*g+0], Y=s_mean[3*g+1], Z=s_mean[3*g+2];
            float cz = R20*X + R21*Y + R22*Z + t2;
            d = fmaxf(cz, 1.0f);
        }
        s_depth[g] = d;
    }
    __syncthreads();

    // ---- projection (wave 0, lane-parallel) ----
    float mx=0.f,my=0.f,qa=0.f,qb=0.f,qc=0.f,lk=0.f,cr=0.f,cg=0.f,cbv=0.f;
    if (w == 0 && lane < nb) {
        int i = g0b + lane;
        float X = s_mean[3*i+0], Y = s_mean[3*i+1], Z = s_mean[3*i+2];
        float cx = R00*X + R01*Y + R02*Z + t0;
        float cy = R10*X + R11*Y + R12*Z + t1;
        float cz = R20*X + R21*Y + R22*Z + t2;
        float depth = s_depth[i];

        float K00=Km[0],K01=Km[1],K02=Km[2];
        float K10=Km[3],K11=Km[4],K12=Km[5];
        float K20=Km[6],K21=Km[7],K22=Km[8];
        float sx = K00*cx + K01*cy + K02*cz;
        float sy = K10*cx + K11*cy + K12*cz;
        float sz = K20*cx + K21*cy + K22*cz;
        mx = sx / sz;
        my = sy / sz;

        float fx = K00, fy = K11;
        float invz  = 1.0f / cz;
        float invz2 = invz * invz;
        float j00 =  fx * invz;
        float j02 = -fx * cx * invz2;
        float j11 =  fy * invz;
        float j12 = -fy * cy * invz2;

        const float* S = s_cov + 9*lane;
        float S00=S[0],S01=S[1],S02=S[2];
        float S10=S[3],S11=S[4],S12=S[5];
        float S20=S[6],S21=S[7],S22=S[8];

        float M00 = R00*S00 + R01*S10 + R02*S20;
        float M01 = R00*S01 + R01*S11 + R02*S21;
        float M02 = R00*S02 + R01*S12 + R02*S22;
        float M10 = R10*S00 + R11*S10 + R12*S20;
        float M11 = R10*S01 + R11*S11 + R12*S21;
        float M12 = R10*S02 + R11*S12 + R12*S22;
        float M20 = R20*S00 + R21*S10 + R22*S20;
        float M21 = R20*S01 + R21*S11 + R22*S21;
        float M22 = R20*S02 + R21*S12 + R22*S22;
        float C00 = M00*R00 + M01*R01 + M02*R02;
        float C01 = M00*R10 + M01*R11 + M02*R12;
        float C02 = M00*R20 + M01*R21 + M02*R22;
        float C11 = M10*R10 + M11*R11 + M12*R12;
        float C12 = M10*R20 + M11*R21 + M12*R22;
        float C22 = M20*R20 + M21*R21 + M22*R22;

        float a_ = j00*j00*C00 + 2.0f*j00*j02*C02 + j02*j02*C22 + EPS2D;
        float b_ = j00*j11*C01 + j00*j12*C02 + j02*j11*C12 + j02*j12*C22;
        float c_ = j11*j11*C11 + 2.0f*j11*j12*C12 + j12*j12*C22 + EPS2D;

        float det = a_ * c_ - b_ * b_;
        float ia =  c_ / det;
        float ib = -b_ / det;
        float ic =  a_ / det;
        float norm = 1.0f / (6.283185307179586f * sqrtf(det));

        bool valid = (depth > 1.0f) && (depth < 50.0f);
        float k = s_op[lane] * norm * (valid ? 1.0f : 0.0f);

        const float NL = -0.72134752044448170368f; // -0.5 * log2(e)
        qa = NL * ia;
        qb = 2.0f * NL * ib;
        qc = NL * ic;
        lk = log2f(k);
        cr = s_col[3*lane+0];
        cg = s_col[3*lane+1];
        cbv = s_col[3*lane+2];
    }

    // ---- partial rank: wave w scans depth quarter [256w, 256w+256) ----
    {
        int cnt = 0;
        if (lane < nb) {
            int i = g0b + lane;
            float d = s_depth[i];
            const float4* d4 = (const float4*)s_depth;
            int jb = w * 64;                 // float4 index base
            #pragma unroll 4
            for (int jj = 0; jj < 64; ++jj) {
                float4 v = d4[jb + jj];       // wave-uniform -> broadcast
                int j = (jb + jj) << 2;
                cnt += (v.x < d || (v.x == d && j+0 < i)) ? 1 : 0;
                cnt += (v.y < d || (v.y == d && j+1 < i)) ? 1 : 0;
                cnt += (v.z < d || (v.z == d && j+2 < i)) ? 1 : 0;
                cnt += (v.w < d || (v.w == d && j+3 < i)) ? 1 : 0;
            }
        }
        s_pr[w][lane] = cnt;
    }
    __syncthreads();

    // ---- combine + scatter (wave 0) ----
    if (w == 0 && lane < nb) {
        int rank = s_pr[0][lane] + s_pr[1][lane] + s_pr[2][lane] + s_pr[3][lane];
        A[rank] = make_float4(mx, my, qa, qb);
        B[rank] = make_float4(qc, lk, cr, cg);
        C[rank] = cbv;
    }
}

// Render: grid = 256 blocks (one per row), 256 threads = 4 waves.
// wave w: x-half = w&1, candidate-half = w>>1 (front/back). Per-wave
// pipelined cull -> idx list -> chunked gather-stage -> composite
// 2 px/thread. One __syncthreads to merge front/back halves via LDS.
__global__ __launch_bounds__(256) void render_kernel(
    const float4* __restrict__ A, const float4* __restrict__ B,
    const float* __restrict__ C, float* __restrict__ out, int n)
{
    __shared__ int    s_idx[4][512];
    __shared__ float4 s_ga[4][64];
    __shared__ float4 s_gb[4][64];
    __shared__ float  s_gc[4][64];
    __shared__ float4 s_part[256];

    int t = threadIdx.x, lane = t & 63, w = t >> 6;
    int row  = blockIdx.x;
    int xh   = w & 1;
    int half = w >> 1;
    int nh   = (n + 1) >> 1;
    int c0   = half ? nh : 0;
    int c1   = half ? n  : nh;

    float xlo = (float)(xh << 7);
    float xhi = xlo + 127.0f;
    float pyf = (float)row;

    // ---- pipelined cull -> order-stable idx list ----
    int cnt = 0;
    if (c1 > c0) {
        int j = c0 + lane;
        int jc = j < c1 ? j : c1 - 1;
        float4 a = A[jc];
        float4 b = B[jc];
        for (int c = c0; c < c1; c += 64) {
            // prefetch next chunk
            float4 a_n, b_n;
            int cn = c + 64;
            if (cn < c1) {
                int j2 = cn + lane;
                int jc2 = j2 < c1 ? j2 : c1 - 1;
                a_n = A[jc2];
                b_n = B[jc2];
            }
            bool keep = false;
            int jj = c + lane;
            if (jj < c1) {
                float cc = b.y + CULL_THR;          // lk + THR
                if (cc > 0.0f) {
                    float dpp = fmaf(4.0f*a.z, b.x, -a.w*a.w);  // 4*qa*qc - qb^2
                    float inv = cc / dpp;
                    float dxe = sqrtf(fmaxf(-4.0f*b.x*inv, 0.0f));
                    float dye = sqrtf(fmaxf(-4.0f*a.z*inv, 0.0f));
                    keep = (a.x + dxe >= xlo) && (a.x - dxe <= xhi) &&
                           (a.y + dye >= pyf) && (a.y - dye <= pyf);
                }
            }
            unsigned long long mk = __ballot(keep);
            int pre = __popcll(mk & ((1ull << lane) - 1ull));
            if (keep) s_idx[w][cnt + pre] = jj;
            cnt += __popcll(mk);
            a = a_n; b = b_n;
        }
    }

    // ---- chunked gather-stage + composite (wave-private) ----
    float x0 = xlo + (float)lane;
    float T0=1.f, T1=1.f;
    float r0=0.f, g0=0.f, b0=0.f, r1=0.f, g1=0.f, b1=0.f;

    for (int k0 = 0; k0 < cnt; k0 += 64) {
        int m = cnt - k0; if (m > 64) m = 64;
        if (lane < m) {
            int jj = s_idx[w][k0 + lane];
            s_ga[w][lane] = A[jj];
            s_gb[w][lane] = B[jj];
            s_gc[w][lane] = C[jj];
        }
        for (int k = 0; k < m; ++k) {
            float4 va = s_ga[w][k];
            float4 vb = s_gb[w][k];
            float  cc = s_gc[w][k];

            float dy   = pyf - va.y;
            float qbdy = va.w * dy;
            float u    = fmaf(vb.x * dy, dy, vb.y);
            float dx0  = x0 - va.x;
            {
                float q = fmaf(fmaf(va.z, dx0, qbdy), dx0, u);
                float e = __builtin_amdgcn_exp2f(q);
                float wg = T0 * e;
                r0 = fmaf(wg, vb.z, r0); g0 = fmaf(wg, vb.w, g0);
                b0 = fmaf(wg, cc, b0);  T0 -= wg;
            }
            {
                float dx1 = dx0 + 64.0f;
                float q = fmaf(fmaf(va.z, dx1, qbdy), dx1, u);
                float e = __builtin_amdgcn_exp2f(q);
                float wg = T1 * e;
                r1 = fmaf(wg, vb.z, r1); g1 = fmaf(wg, vb.w, g1);
                b1 = fmaf(wg, cc, b1);  T1 -= wg;
            }
            if ((k & 15) == 15) {
                if (__all(fmaxf(T0, T1) < RTHR)) break;
            }
        }
        if (__all(fmaxf(T0, T1) < RTHR)) break;
    }

    // ---- merge front/back through LDS ----
    int lpx = (xh << 7) + lane;          // local pixel x (0..255)
    if (half) {
        s_part[lpx]      = make_float4(r0, g0, b0, T0);
        s_part[lpx + 64] = make_float4(r1, g1, b1, T1);
    }
    __syncthreads();
    if (!half) {
        float4 p0 = s_part[lpx];
        float4 p1 = s_part[lpx + 64];
        int p = row * 256 + lpx;
        out[3*p+0] = fmaf(T0, p0.x, r0);
        out[3*p+1] = fmaf(T0, p0.y, g0);
        out[3*p+2] = fmaf(T0, p0.z, b0);
        p += 64;
        out[3*p+0] = fmaf(T1, p1.x, r1);
        out[3*p+1] = fmaf(T1, p1.y, g1);
        out[3*p+2] = fmaf(T1, p1.z, b1);
    }
}

extern "C" void kernel_launch(void* const* d_in, const int* in_sizes, int n_in,
                              void* d_out, int out_size, void* d_ws, size_t ws_size,
                              hipStream_t stream)
{
    const float* means3D = (const float*)d_in[0];
    const float* covs3d  = (const float*)d_in[1];
    const float* colors  = (const float*)d_in[2];
    const float* opac    = (const float*)d_in[3];
    const float* Km      = (const float*)d_in[4];
    const float* Rm      = (const float*)d_in[5];
    const float* tv      = (const float*)d_in[6];
    int n = in_sizes[3];
    if (n > MAXN) n = MAXN;

    float4* A = (float4*)d_ws;                          // 16 KB
    float4* B = (float4*)((char*)d_ws + 16384);         // 16 KB
    float*  C = (float*)((char*)d_ws + 32768);          // 4 KB

    int pblocks = (n + 63) / 64;
    hipLaunchKernelGGL(prep_kernel, dim3(pblocks), dim3(256), 0, stream,
                       means3D, covs3d, colors, opac, Km, Rm, tv, A, B, C, n);

    hipLaunchKernelGGL(render_kernel, dim3(HH), dim3(256), 0, stream,
                       A, B, C, (float*)d_out, n);
}

// Round 8
// 23.853 us; speedup vs baseline: 3.0122x; 1.3399x over previous
//
#include <hip/hip_runtime.h>
#include <math.h>

#define HH 256
#define WW 256
#define EPS2D 1e-4f
#define MAXN 1024
#define CULL_THR 23.0f   // skip gaussian in a row if max alpha there < 2^-23
#define NL_HALF_LOG2E -0.72134752044448170368f

// SoA records, depth-sorted front-to-back (in d_ws):
//   A[g] = (mx, my, qa, qb)   B[g] = (qc, lk, cr, cg)   C[g] = cb
// alpha = exp2( qa*dx*dx + qb*dx*dy + qc*dy*dy + lk ),  qa,qc < 0

// prep: grid = ceil(n/64) blocks x 256 threads (4 waves).
// Block b owns gaussians [64b, 64b+64). Wave w computes partial ranks over
// depth quarter [256w, 256w+256); wave 0 does projection lane-parallel.
__global__ __launch_bounds__(256) void prep_kernel(
    const float* __restrict__ means3D, const float* __restrict__ covs3d,
    const float* __restrict__ colors,  const float* __restrict__ opac,
    const float* __restrict__ Km,      const float* __restrict__ Rm,
    const float* __restrict__ tv,
    float4* __restrict__ A, float4* __restrict__ B, float* __restrict__ C,
    int n)
{
    __shared__ float s_mean[MAXN*3];   // all means (12 KB)
    __shared__ float s_depth[MAXN];    // all depths (4 KB)
    __shared__ float s_cov[64*9];
    __shared__ float s_col[64*3];
    __shared__ float s_op[64];
    __shared__ int   s_pr[4][64];

    int t = threadIdx.x, lane = t & 63, w = t >> 6;
    int g0b = blockIdx.x * 64;
    int nb = n - g0b; if (nb > 64) nb = 64; if (nb < 0) nb = 0;

    // ---- coalesced staging ----
    {
        int nm4 = (3*n) >> 2;
        const float4* m4 = (const float4*)means3D;
        for (int i = t; i < nm4; i += 256) ((float4*)s_mean)[i] = m4[i];
        for (int i = (nm4<<2) + t; i < 3*n; i += 256) s_mean[i] = means3D[i];

        const float* cbase = covs3d + (size_t)g0b * 9;
        int ncf = nb * 9, nc4 = ncf >> 2;
        for (int i = t; i < nc4; i += 256) ((float4*)s_cov)[i] = ((const float4*)cbase)[i];
        for (int i = (nc4<<2) + t; i < ncf; i += 256) s_cov[i] = cbase[i];

        const float* lbase = colors + (size_t)g0b * 3;
        int nlf = nb * 3, nl4 = nlf >> 2;
        for (int i = t; i < nl4; i += 256) ((float4*)s_col)[i] = ((const float4*)lbase)[i];
        for (int i = (nl4<<2) + t; i < nlf; i += 256) s_col[i] = lbase[i];

        const float* obase = opac + g0b;
        int no4 = nb >> 2;
        for (int i = t; i < no4; i += 256) ((float4*)s_op)[i] = ((const float4*)obase)[i];
        for (int i = (no4<<2) + t; i < nb; i += 256) s_op[i] = obase[i];
    }
    __syncthreads();

    float R00=Rm[0],R01=Rm[1],R02=Rm[2];
    float R10=Rm[3],R11=Rm[4],R12=Rm[5];
    float R20=Rm[6],R21=Rm[7],R22=Rm[8];
    float t0=tv[0], t1=tv[1], t2=tv[2];

    // ---- all depths ----
    for (int g = t; g < MAXN; g += 256) {
        float d = 1e30f;
        if (g < n) {
            float X=s_mean[3*g+0], Y=s_mean[3*g+1], Z=s_mean[3*g+2];
            float cz = R20*X + R21*Y + R22*Z + t2;
            d = fmaxf(cz, 1.0f);
        }
        s_depth[g] = d;
    }
    __syncthreads();

    // ---- projection (wave 0, lane-parallel) ----
    float mx=0.f,my=0.f,qa=0.f,qb=0.f,qc=0.f,lk=0.f,cr=0.f,cg=0.f,cbv=0.f;
    if (w == 0 && lane < nb) {
        int i = g0b + lane;
        float X = s_mean[3*i+0], Y = s_mean[3*i+1], Z = s_mean[3*i+2];
        float cx = R00*X + R01*Y + R02*Z + t0;
        float cy = R10*X + R11*Y + R12*Z + t1;
        float cz = R20*X + R21*Y + R22*Z + t2;
        float depth = s_depth[i];

        float K00=Km[0],K01=Km[1],K02=Km[2];
        float K10=Km[3],K11=Km[4],K12=Km[5];
        float K20=Km[6],K21=Km[7],K22=Km[8];
        float sx = K00*cx + K01*cy + K02*cz;
        float sy = K10*cx + K11*cy + K12*cz;
        float sz = K20*cx + K21*cy + K22*cz;
        mx = sx / sz;
        my = sy / sz;

        float fx = K00, fy = K11;
        float invz  = 1.0f / cz;
        float invz2 = invz * invz;
        float j00 =  fx * invz;
        float j02 = -fx * cx * invz2;
        float j11 =  fy * invz;
        float j12 = -fy * cy * invz2;

        const float* S = s_cov + 9*lane;
        float S00=S[0],S01=S[1],S02=S[2];
        float S10=S[3],S11=S[4],S12=S[5];
        float S20=S[6],S21=S[7],S22=S[8];

        float M00 = R00*S00 + R01*S10 + R02*S20;
        float M01 = R00*S01 + R01*S11 + R02*S21;
        float M02 = R00*S02 + R01*S12 + R02*S22;
        float M10 = R10*S00 + R11*S10 + R12*S20;
        float M11 = R10*S01 + R11*S11 + R12*S21;
        float M12 = R10*S02 + R11*S12 + R12*S22;
        float M20 = R20*S00 + R21*S10 + R22*S20;
        float M21 = R20*S01 + R21*S11 + R22*S21;
        float M22 = R20*S02 + R21*S12 + R22*S22;
        float C00 = M00*R00 + M01*R01 + M02*R02;
        float C01 = M00*R10 + M01*R11 + M02*R12;
        float C02 = M00*R20 + M01*R21 + M02*R22;
        float C11 = M10*R10 + M11*R11 + M12*R12;
        float C12 = M10*R20 + M11*R21 + M12*R22;
        float C22 = M20*R20 + M21*R21 + M22*R22;

        float a_ = j00*j00*C00 + 2.0f*j00*j02*C02 + j02*j02*C22 + EPS2D;
        float b_ = j00*j11*C01 + j00*j12*C02 + j02*j11*C12 + j02*j12*C22;
        float c_ = j11*j11*C11 + 2.0f*j11*j12*C12 + j12*j12*C22 + EPS2D;

        float det = a_ * c_ - b_ * b_;
        float ia =  c_ / det;
        float ib = -b_ / det;
        float ic =  a_ / det;
        float norm = 1.0f / (6.283185307179586f * sqrtf(det));

        bool valid = (depth > 1.0f) && (depth < 50.0f);
        float k = s_op[lane] * norm * (valid ? 1.0f : 0.0f);

        qa = NL_HALF_LOG2E * ia;
        qb = 2.0f * NL_HALF_LOG2E * ib;
        qc = NL_HALF_LOG2E * ic;
        lk = log2f(k);
        cr = s_col[3*lane+0];
        cg = s_col[3*lane+1];
        cbv = s_col[3*lane+2];
    }

    // ---- partial rank: wave w scans depth quarter [256w, 256w+256) ----
    {
        int cnt = 0;
        if (lane < nb) {
            int i = g0b + lane;
            float d = s_depth[i];
            const float4* d4 = (const float4*)s_depth;
            int jb = w * 64;                 // float4 index base
            #pragma unroll 4
            for (int jj = 0; jj < 64; ++jj) {
                float4 v = d4[jb + jj];       // wave-uniform -> broadcast
                int j = (jb + jj) << 2;
                cnt += (v.x < d || (v.x == d && j+0 < i)) ? 1 : 0;
                cnt += (v.y < d || (v.y == d && j+1 < i)) ? 1 : 0;
                cnt += (v.z < d || (v.z == d && j+2 < i)) ? 1 : 0;
                cnt += (v.w < d || (v.w == d && j+3 < i)) ? 1 : 0;
            }
        }
        s_pr[w][lane] = cnt;
    }
    __syncthreads();

    // ---- combine + scatter (wave 0) ----
    if (w == 0 && lane < nb) {
        int rank = s_pr[0][lane] + s_pr[1][lane] + s_pr[2][lane] + s_pr[3][lane];
        A[rank] = make_float4(mx, my, qa, qb);
        B[rank] = make_float4(qc, lk, cr, cg);
        C[rank] = cbv;
    }
}

// Render: grid = 256 blocks (one per row), 256 threads = 4 waves.
// wave w handles depth-quarter [n*w/4, n*(w+1)/4) over the FULL row,
// 4 px/thread (x = lane + 64*i). Pipelined cull -> idx list -> staged
// composite with row-constants hoisted. One barrier to merge quarters.
__global__ __launch_bounds__(256) void render_kernel(
    const float4* __restrict__ A, const float4* __restrict__ B,
    const float* __restrict__ C, float* __restrict__ out, int n)
{
    __shared__ int    s_idx[4][256];
    __shared__ float4 s_p0[4][64];
    __shared__ float4 s_p1[4][64];
    __shared__ float4 s_part[3][256];

    int t = threadIdx.x, lane = t & 63, w = t >> 6;
    int row = blockIdx.x;
    int q0 = (n *  w     ) >> 2;
    int q1 = (n * (w + 1)) >> 2;
    float pyf = (float)row;

    // ---- pipelined cull -> order-stable idx list ----
    int cnt = 0;
    if (q1 > q0) {
        int jc = min(q0 + lane, q1 - 1);
        float4 a = A[jc];
        float4 b = B[jc];
        for (int c = q0; c < q1; c += 64) {
            float4 a_n, b_n;
            int cn = c + 64;
            if (cn < q1) {
                int jc2 = min(cn + lane, q1 - 1);
                a_n = A[jc2];
                b_n = B[jc2];
            }
            int jj = c + lane;
            bool keep = false;
            if (jj < q1) {
                float cc = b.y + CULL_THR;          // lk + THR
                if (cc > 0.0f) {
                    float dpp = fmaf(4.0f*a.z, b.x, -a.w*a.w);  // 4*qa*qc - qb^2
                    float inv = cc / dpp;
                    float dxe = sqrtf(fmaxf(-4.0f*b.x*inv, 0.0f));
                    float dye = sqrtf(fmaxf(-4.0f*a.z*inv, 0.0f));
                    keep = (a.x + dxe >= 0.0f) && (a.x - dxe <= 255.0f) &&
                           (a.y + dye >= pyf)  && (a.y - dye <= pyf);
                }
            }
            unsigned long long mk = __ballot(keep);
            int pre = __popcll(mk & ((1ull << lane) - 1ull));
            if (keep) s_idx[w][cnt + pre] = jj;
            cnt += __popcll(mk);
            a = a_n; b = b_n;
        }
    }

    // ---- staged composite, 4 px/thread ----
    float lanef = (float)lane;
    float T0=1.f,T1=1.f,T2=1.f,T3=1.f;
    float r0=0.f,g0=0.f,b0=0.f, r1=0.f,g1=0.f,b1=0.f;
    float r2=0.f,g2=0.f,b2=0.f, r3=0.f,g3=0.f,b3=0.f;

    for (int k0 = 0; k0 < cnt; k0 += 64) {
        int m = cnt - k0; if (m > 64) m = 64;
        if (lane < m) {
            int jj = s_idx[w][k0 + lane];
            float4 a  = A[jj];
            float4 bb = B[jj];
            float  cc = C[jj];
            float dy = pyf - a.y;
            // (mx, qa, qb*dy, qc*dy^2+lk) ; (cr, cg, cb, -)
            s_p0[w][lane] = make_float4(a.x, a.z, a.w * dy,
                                        fmaf(bb.x * dy, dy, bb.y));
            s_p1[w][lane] = make_float4(bb.z, bb.w, cc, 0.f);
        }
        for (int k = 0; k < m; ++k) {
            float4 p0 = s_p0[w][k];
            float4 p1 = s_p1[w][k];
            float dx = lanef - p0.x;
            {
                float q = fmaf(fmaf(p0.y, dx, p0.z), dx, p0.w);
                float wg = T0 * __builtin_amdgcn_exp2f(q);
                r0 = fmaf(wg, p1.x, r0); g0 = fmaf(wg, p1.y, g0);
                b0 = fmaf(wg, p1.z, b0); T0 -= wg;
            }
            dx += 64.0f;
            {
                float q = fmaf(fmaf(p0.y, dx, p0.z), dx, p0.w);
                float wg = T1 * __builtin_amdgcn_exp2f(q);
                r1 = fmaf(wg, p1.x, r1); g1 = fmaf(wg, p1.y, g1);
                b1 = fmaf(wg, p1.z, b1); T1 -= wg;
            }
            dx += 64.0f;
            {
                float q = fmaf(fmaf(p0.y, dx, p0.z), dx, p0.w);
                float wg = T2 * __builtin_amdgcn_exp2f(q);
                r2 = fmaf(wg, p1.x, r2); g2 = fmaf(wg, p1.y, g2);
                b2 = fmaf(wg, p1.z, b2); T2 -= wg;
            }
            dx += 64.0f;
            {
                float q = fmaf(fmaf(p0.y, dx, p0.z), dx, p0.w);
                float wg = T3 * __builtin_amdgcn_exp2f(q);
                r3 = fmaf(wg, p1.x, r3); g3 = fmaf(wg, p1.y, g3);
                b3 = fmaf(wg, p1.z, b3); T3 -= wg;
            }
        }
    }

    // ---- merge quarters: final = P0 . P1 . P2 . P3 ----
    if (w != 0) {
        s_part[w-1][lane +   0] = make_float4(r0, g0, b0, T0);
        s_part[w-1][lane +  64] = make_float4(r1, g1, b1, T1);
        s_part[w-1][lane + 128] = make_float4(r2, g2, b2, T2);
        s_part[w-1][lane + 192] = make_float4(r3, g3, b3, T3);
    }
    __syncthreads();
    if (w == 0) {
        float rr[4] = {r0, r1, r2, r3};
        float gg[4] = {g0, g1, g2, g3};
        float bbv[4] = {b0, b1, b2, b3};
        float tt[4] = {T0, T1, T2, T3};
        #pragma unroll
        for (int i = 0; i < 4; ++i) {
            int px = lane + (i << 6);
            float4 m1 = s_part[0][px];
            float4 m2 = s_part[1][px];
            float4 m3 = s_part[2][px];
            // chain back-to-front: P2.P3 then P1.(..) then P0.(..)
            float cr = m2.x + m2.w * m3.x;
            float cg = m2.y + m2.w * m3.y;
            float cb = m2.z + m2.w * m3.z;
            cr = m1.x + m1.w * cr;
            cg = m1.y + m1.w * cg;
            cb = m1.z + m1.w * cb;
            cr = rr[i] + tt[i] * cr;
            cg = gg[i] + tt[i] * cg;
            cb = bbv[i] + tt[i] * cb;
            int p = row * 256 + px;
            out[3*p+0] = cr;
            out[3*p+1] = cg;
            out[3*p+2] = cb;
        }
    }
}

extern "C" void kernel_launch(void* const* d_in, const int* in_sizes, int n_in,
                              void* d_out, int out_size, void* d_ws, size_t ws_size,
                              hipStream_t stream)
{
    const float* means3D = (const float*)d_in[0];
    const float* covs3d  = (const float*)d_in[1];
    const float* colors  = (const float*)d_in[2];
    const float* opac    = (const float*)d_in[3];
    const float* Km      = (const float*)d_in[4];
    const float* Rm      = (const float*)d_in[5];
    const float* tv      = (const float*)d_in[6];
    int n = in_sizes[3];
    if (n > MAXN) n = MAXN;

    float4* A = (float4*)d_ws;                          // 16 KB
    float4* B = (float4*)((char*)d_ws + 16384);         // 16 KB
    float*  C = (float*)((char*)d_ws + 32768);          // 4 KB

    int pblocks = (n + 63) / 64;
    hipLaunchKernelGGL(prep_kernel, dim3(pblocks), dim3(256), 0, stream,
                       means3D, covs3d, colors, opac, Km, Rm, tv, A, B, C, n);

    hipLaunchKernelGGL(render_kernel, dim3(HH), dim3(256), 0, stream,
                       A, B, C, (float*)d_out, n);
}